// Round 3
// baseline (36.263 us; speedup 1.0000x reference)
//
#include <hip/hip_runtime.h>

// GIoU max-match loss: out = (1/B) * sum_{b,p} (1 - max_g GIoU(pred[b,p], tgt[b,g]))
// B=32, P=2048, G=512 in the bench shapes (derived at runtime from in_sizes).
//
// Structure:
//   prep kernel: tgt boxes -> 32B records {x1, y1, x2+1, y2+1, area} in d_ws.
//   partial kernel: block = 512 threads = 8 waves, covers 64 preds (lane = pred).
//     Wave w scans G/8 targets; target records are read at WAVE-UNIFORM
//     addresses -> compiler emits s_load (SMEM pipe, SGPRs), so the inner
//     loop has zero LDS and zero vector-memory traffic. Cross-wave max via
//     LDS, then 2-kernel deterministic sum.
// Math notes: boxes have w,h >= 1 so outer-dims need no clamp and union>0;
//   gi is tracked as iou + un/outer (= giou+1) in (0,2]; the reference's
//   clip to [-1,1] and iou-eps floor are no-ops at the 42.24 absmax threshold.

__global__ __launch_bounds__(256) void giou_prep_kernel(
    const float4* __restrict__ tgt,   // (B*G) boxes
    float4* __restrict__ recs,        // (B*G) pairs of float4: {box_shifted, area}
    int n)
{
    int i = blockIdx.x * 256 + threadIdx.x;
    if (i < n) {
        float4 t = tgt[i];
        t.z += 1.0f; t.w += 1.0f;     // pre-shift: fold the +1 width convention
        float area = fmaxf(t.z - t.x, 0.0f) * fmaxf(t.w - t.y, 0.0f);
        recs[2 * i]     = t;
        recs[2 * i + 1] = make_float4(area, 0.0f, 0.0f, 0.0f);
    }
}

__global__ __launch_bounds__(512) void giou_partial_kernel(
    const float4* __restrict__ recs,   // (B, G) 32B records
    const float4* __restrict__ pred,   // (B, P) boxes
    float* __restrict__ partial,       // one partial sum per block
    int P, int G)
{
    __shared__ float sM[512];

    const int b    = blockIdx.y;
    const int tid  = threadIdx.x;
    const int lane = tid & 63;
    // readfirstlane: make the wave id PROVABLY uniform so the g-loop bounds
    // and record addresses are uniform -> scalar (s_load) memory path.
    const int wid  = __builtin_amdgcn_readfirstlane(tid >> 6);

    const int p = blockIdx.x * 64 + lane;
    float4 pb = pred[b * P + min(p, P - 1)];
    pb.z += 1.0f; pb.w += 1.0f;
    float pa = fmaxf(pb.z - pb.x, 0.0f) * fmaxf(pb.w - pb.y, 0.0f);

    const float4* __restrict__ base = recs + (size_t)(2 * b) * G;

    const int gq = (G + 7) >> 3;           // targets per wave
    const int g0 = wid * gq;
    const int g1 = min(g0 + gq, G);

    // m tracks max over g of (giou + 1) in (0, 2]; 0 is a safe identity.
    float m = 0.0f;

    #pragma unroll 4
    for (int g = g0; g < g1; ++g) {
        float4 t  = base[2 * g];           // uniform addr -> s_load_dwordx4
        float  ta = base[2 * g + 1].x;     // uniform addr -> s_load

        float ix1 = fmaxf(pb.x, t.x);
        float iy1 = fmaxf(pb.y, t.y);
        float ix2 = fminf(pb.z, t.z);
        float iy2 = fminf(pb.w, t.w);
        float iw  = fmaxf(ix2 - ix1, 0.0f);
        float ih  = fmaxf(iy2 - iy1, 0.0f);
        float inter = iw * ih;

        float un  = (pa + ta) - inter;     // >= max(pa,ta) >= 1
        float iou = inter * __builtin_amdgcn_rcpf(un);

        float ox1 = fminf(pb.x, t.x);
        float oy1 = fminf(pb.y, t.y);
        float ox2 = fmaxf(pb.z, t.z);
        float oy2 = fmaxf(pb.w, t.w);
        float outer = (ox2 - ox1) * (oy2 - oy1);   // >= pa > 0, no clamp needed

        // giou + 1 = iou + un/outer
        float gi = __builtin_fmaf(un, __builtin_amdgcn_rcpf(outer), iou);
        m = fmaxf(m, gi);
    }

    sM[tid] = m;
    __syncthreads();

    if (wid == 0) {
        float mm = sM[lane];
        #pragma unroll
        for (int w = 1; w < 8; ++w) mm = fmaxf(mm, sM[lane + 64 * w]);
        // per-pred loss = 1 - giou = 2 - mm; zero out lanes past P (p>=P)
        float v = (p < P) ? (2.0f - mm) : 0.0f;
        #pragma unroll
        for (int off = 32; off > 0; off >>= 1)
            v += __shfl_down(v, off, 64);
        if (lane == 0)
            partial[blockIdx.y * gridDim.x + blockIdx.x] = v;
    }
}

__global__ __launch_bounds__(256) void giou_reduce_kernel(
    const float* __restrict__ partial, float* __restrict__ out, int n, float invB)
{
    const int tid = threadIdx.x;
    float v = 0.0f;
    for (int i = tid; i < n; i += 256) v += partial[i];

    #pragma unroll
    for (int off = 32; off > 0; off >>= 1)
        v += __shfl_down(v, off, 64);

    __shared__ float sW[4];
    const int wid = tid >> 6;
    if ((tid & 63) == 0) sW[wid] = v;
    __syncthreads();
    if (tid == 0)
        out[0] = (sW[0] + sW[1] + sW[2] + sW[3]) * invB;
}

extern "C" void kernel_launch(void* const* d_in, const int* in_sizes, int n_in,
                              void* d_out, int out_size, void* d_ws, size_t ws_size,
                              hipStream_t stream) {
    const float* imgs_box = (const float*)d_in[0];  // (B, G, 4) fp32
    const float* pre_box  = (const float*)d_in[1];  // (B, P, 4) fp32
    // d_in[2] = labels, only its length (B) matters.

    const int B = in_sizes[2];
    const int G = in_sizes[0] / (4 * B);
    const int P = in_sizes[1] / (4 * B);

    const int nrec = B * G;
    float4* recs = (float4*)d_ws;                               // nrec * 32B
    float*  partial = (float*)((char*)d_ws + (size_t)nrec * 32); // pblocks*B floats

    giou_prep_kernel<<<(nrec + 255) / 256, 256, 0, stream>>>(
        (const float4*)imgs_box, recs, nrec);

    const int pblocks = (P + 63) / 64;               // 64 preds per block
    dim3 grid(pblocks, B);
    giou_partial_kernel<<<grid, 512, 0, stream>>>(
        (const float4*)recs, (const float4*)pre_box, partial, P, G);

    const int n = pblocks * B;
    giou_reduce_kernel<<<1, 256, 0, stream>>>(partial, (float*)d_out, n, 1.0f / (float)B);
}

// Round 4
// 30.771 us; speedup vs baseline: 1.1785x; 1.1785x over previous
//
#include <hip/hip_runtime.h>

// GIoU max-match loss: out = (1/B) * sum_{b,p} (1 - max_g GIoU(pred[b,p], tgt[b,g]))
// B=32, P=2048, G=512 in the bench shapes (derived at runtime from in_sizes).
//
// Structure: block = 512 threads = 8 waves, covers 128 preds.
//   Lane l owns preds (blk*128 + l) and (blk*128 + 64 + l)  [2-pred register
//   blocking: halves LDS issue per pair — R2 was LDS-pipe-bound at 1 pred/lane].
//   Wave w scans targets [w*G/8, (w+1)*G/8); targets+areas staged in LDS,
//   read at wave-broadcast addresses (no bank conflicts).
//   Cross-wave max via LDS, then a second tiny kernel does the final sum.
// Math notes: boxes have w,h >= 1 so outer dims need no clamp and union >= 1;
//   gi tracks (giou + 1) = iou + un/outer in (0,2]; the reference's clip to
//   [-1,1] and the 1e-6 iou floor are no-ops at the 42.24 absmax threshold.

__global__ __launch_bounds__(512) void giou_partial_kernel(
    const float4* __restrict__ tgt,    // (B, G) boxes as float4 (x1,y1,x2,y2)
    const float4* __restrict__ pred,   // (B, P) boxes as float4
    float* __restrict__ partial,       // one partial sum per block
    int P, int G)
{
    __shared__ float4 sT[512];    // pre-shifted target boxes
    __shared__ float  sA[512];    // target areas
    __shared__ float  sM[1024];   // cross-wave max exchange (2 preds/lane)

    const int b    = blockIdx.y;
    const int tid  = threadIdx.x;
    const int lane = tid & 63;
    const int wid  = tid >> 6;

    // Stage this batch's target boxes + areas into LDS (coalesced float4 loads).
    for (int g = tid; g < G; g += 512) {
        float4 t = tgt[b * G + g];
        t.z += 1.0f; t.w += 1.0f;                    // fold the +1 convention
        sT[g] = t;
        sA[g] = (t.z - t.x) * (t.w - t.y);           // w,h >= 1: no clamp
    }
    __syncthreads();

    const int p0 = blockIdx.x * 128 + lane;
    const int p1 = p0 + 64;
    float4 pb0 = pred[b * P + min(p0, P - 1)];
    float4 pb1 = pred[b * P + min(p1, P - 1)];
    pb0.z += 1.0f; pb0.w += 1.0f;
    pb1.z += 1.0f; pb1.w += 1.0f;
    const float pa0 = (pb0.z - pb0.x) * (pb0.w - pb0.y);
    const float pa1 = (pb1.z - pb1.x) * (pb1.w - pb1.y);

    const int gq = (G + 7) >> 3;           // targets per wave
    const int g0 = wid * gq;
    const int g1 = min(g0 + gq, G);

    // m* track max over g of (giou + 1) in (0, 2]; 0 is a safe identity.
    float m0 = 0.0f, m1 = 0.0f;

    #pragma unroll 4
    for (int g = g0; g < g1; ++g) {
        const float4 t  = sT[g];           // broadcast ds_read_b128
        const float  ta = sA[g];           // broadcast ds_read_b32

        { // pred 0
            float iw = fmaxf(fminf(pb0.z, t.z) - fmaxf(pb0.x, t.x), 0.0f);
            float ih = fmaxf(fminf(pb0.w, t.w) - fmaxf(pb0.y, t.y), 0.0f);
            float inter = iw * ih;
            float un  = (pa0 + ta) - inter;
            float iou = inter * __builtin_amdgcn_rcpf(un);
            float ow  = fmaxf(pb0.z, t.z) - fminf(pb0.x, t.x);
            float oh  = fmaxf(pb0.w, t.w) - fminf(pb0.y, t.y);
            float gi  = __builtin_fmaf(un, __builtin_amdgcn_rcpf(ow * oh), iou);
            m0 = fmaxf(m0, gi);
        }
        { // pred 1
            float iw = fmaxf(fminf(pb1.z, t.z) - fmaxf(pb1.x, t.x), 0.0f);
            float ih = fmaxf(fminf(pb1.w, t.w) - fmaxf(pb1.y, t.y), 0.0f);
            float inter = iw * ih;
            float un  = (pa1 + ta) - inter;
            float iou = inter * __builtin_amdgcn_rcpf(un);
            float ow  = fmaxf(pb1.z, t.z) - fminf(pb1.x, t.x);
            float oh  = fmaxf(pb1.w, t.w) - fminf(pb1.y, t.y);
            float gi  = __builtin_fmaf(un, __builtin_amdgcn_rcpf(ow * oh), iou);
            m1 = fmaxf(m1, gi);
        }
    }

    sM[tid]       = m0;
    sM[512 + tid] = m1;
    __syncthreads();

    if (wid == 0) {
        float mm0 = sM[lane];
        float mm1 = sM[512 + lane];
        #pragma unroll
        for (int w = 1; w < 8; ++w) {
            mm0 = fmaxf(mm0, sM[w * 64 + lane]);
            mm1 = fmaxf(mm1, sM[512 + w * 64 + lane]);
        }
        // per-pred loss = 1 - giou = 2 - (giou+1)
        float v = ((p0 < P) ? (2.0f - mm0) : 0.0f)
                + ((p1 < P) ? (2.0f - mm1) : 0.0f);
        #pragma unroll
        for (int off = 32; off > 0; off >>= 1)
            v += __shfl_down(v, off, 64);
        if (lane == 0)
            partial[blockIdx.y * gridDim.x + blockIdx.x] = v;
    }
}

__global__ __launch_bounds__(256) void giou_reduce_kernel(
    const float* __restrict__ partial, float* __restrict__ out, int n, float invB)
{
    const int tid = threadIdx.x;
    float v = 0.0f;
    for (int i = tid; i < n; i += 256) v += partial[i];

    #pragma unroll
    for (int off = 32; off > 0; off >>= 1)
        v += __shfl_down(v, off, 64);

    __shared__ float sW[4];
    const int wid = tid >> 6;
    if ((tid & 63) == 0) sW[wid] = v;
    __syncthreads();
    if (tid == 0)
        out[0] = (sW[0] + sW[1] + sW[2] + sW[3]) * invB;
}

extern "C" void kernel_launch(void* const* d_in, const int* in_sizes, int n_in,
                              void* d_out, int out_size, void* d_ws, size_t ws_size,
                              hipStream_t stream) {
    const float* imgs_box = (const float*)d_in[0];  // (B, G, 4) fp32
    const float* pre_box  = (const float*)d_in[1];  // (B, P, 4) fp32
    // d_in[2] = labels, only its length (B) matters.

    const int B = in_sizes[2];
    const int G = in_sizes[0] / (4 * B);
    const int P = in_sizes[1] / (4 * B);

    float* partial = (float*)d_ws;

    const int pblocks = (P + 127) / 128;             // 128 preds per block
    dim3 grid(pblocks, B);
    giou_partial_kernel<<<grid, 512, 0, stream>>>(
        (const float4*)imgs_box, (const float4*)pre_box, partial, P, G);

    const int n = pblocks * B;
    giou_reduce_kernel<<<1, 256, 0, stream>>>(partial, (float*)d_out, n, 1.0f / (float)B);
}